// Round 12
// baseline (140.849 us; speedup 1.0000x reference)
//
#include <hip/hip_runtime.h>

// SpDepthWSepaConv3d: out[i,c] = bias[c] + sum_k mask[k,i] * features[pair_in[k,i],c] * weight[k,c]
// Pure gather (pair_out[k][i]==i when mask set). All int inputs are int32 on device.
//
// R12: remove pair_in from K2's dependent chain. K1 packs a 16B record per
// voxel: .x = bits (bit31 = VERIFIED center tap; bits 0..26 = residual taps,
// including an unverified center), .y/.z/.w = first 3 residual pins in
// ascending-k order (default vox -> always a valid row). K2 residual loop
// rank-selects the pin from the record (VALU popcount, no load); >3 residual
// taps (rare, but correctness-handled) falls back to pair_in.

#define KVOL 27

typedef float vf4 __attribute__((ext_vector_type(4)));

__global__ __launch_bounds__(256) void spconv_meta_kernel(
    const int* __restrict__ pair_in,      // [27, n]
    const int* __restrict__ pair_mask,    // [27, n]
    int4* __restrict__ rec_ws,            // [n] packed records
    int n)
{
    const int vox = blockIdx.x * 256 + threadIdx.x;
    if (vox >= n) return;

    unsigned int bits = 0;
    int pins[3] = {vox, vox, vox};
    int cnt = 0;

    #pragma unroll
    for (int k = 0; k < KVOL; ++k) {
        const int mv = pair_mask[(size_t)k * n + vox];      // coalesced
        if (mv != 0) {
            if (k == 13) {
                const int pin13 = pair_in[(size_t)13 * n + vox];
                if (pin13 == vox) { bits |= 0x80000000u; continue; }  // verified center
                bits |= 1u << 13;                            // unverified -> residual
                if (cnt < 3) pins[cnt] = pin13;
                ++cnt;
            } else {
                bits |= 1u << k;
                if (cnt < 3) pins[cnt] = pair_in[(size_t)k * n + vox]; // predicated, per-k coalesced
                ++cnt;
            }
        }
    }

    rec_ws[vox] = make_int4((int)bits, pins[0], pins[1], pins[2]);
}

// wave = 8 voxels (2 quad-groups of 4), block = 4 waves = 32 consecutive voxels
#define GPW  2
#define VPB  32

__global__ __launch_bounds__(256) void spconv_dw_kernel(
    const float* __restrict__ features,   // [n, 64]
    const float* __restrict__ weight,     // [27, 64]
    const float* __restrict__ bias,       // [64]
    const int* __restrict__ pair_in,      // [27, n] (overflow fallback only)
    const int4* __restrict__ rec_ws,      // [n] packed records
    float* __restrict__ out,              // [n, 64]
    int n)
{
    const int t     = threadIdx.x;
    const int w     = t >> 6;                  // wave in block
    const int lane  = t & 63;
    const int sub   = lane >> 4;               // voxel within quad
    const int c4    = lane & 15;               // float4 index within 64 channels
    const int wbase = blockIdx.x * VPB + w * (GPW * 4);

    int voxl[GPW], voxc[GPW];
    int4 rec[GPW];
    vf4 fc[GPW];
    #pragma unroll
    for (int g = 0; g < GPW; ++g) {
        voxl[g] = wbase + g * 4 + sub;
        voxc[g] = voxl[g] < n ? voxl[g] : (n - 1);            // clamp for loads
        rec[g]  = rec_ws[voxc[g]];                            // 16B record, quad-shared lines
        fc[g]   = ((const vf4*)&features[(size_t)voxc[g] * 64])[c4];  // 1KB/wave
    }

    const vf4 bv  = ((const vf4*)bias)[c4];
    const vf4 w13 = ((const vf4*)&weight[13 * 64])[c4];

    #pragma unroll
    for (int g = 0; g < GPW; ++g) {
        const unsigned int bits = (unsigned int)rec[g].x;

        // verified center tap: per-lane mask-by-multiply
        const float m13 = (bits & 0x80000000u) ? 1.0f : 0.0f;
        vf4 acc = bv + (fc[g] * m13) * w13;

        // residual taps: loop over wave-union of the 4 voxels' tap sets
        unsigned int res = bits & 0x07FFFFFFu;
        unsigned int uni = res | __shfl_xor(res, 16);
        uni |= __shfl_xor(uni, 32);
        uni = __builtin_amdgcn_readfirstlane(uni);

        while (uni) {
            const int k = __builtin_ctz(uni);
            uni &= uni - 1;
            const unsigned int below = res & ((1u << k) - 1u);
            const int r = __popc(below);                       // rank of k in res
            const float sel = (res >> k) & 1u ? 1.0f : 0.0f;
            int pin;
            if (r == 0)      pin = rec[g].y;
            else if (r == 1) pin = rec[g].z;
            else if (r == 2) pin = rec[g].w;
            else             pin = pair_in[(size_t)k * n + voxc[g]];  // rare overflow
            const vf4 f  = ((const vf4*)&features[(size_t)pin * 64])[c4];
            const vf4 wk = ((const vf4*)&weight[k * 64])[c4];
            acc += (f * sel) * wk;
        }

        if (voxl[g] < n)
            __builtin_nontemporal_store(acc,
                (vf4*)&out[(size_t)voxl[g] * 64 + c4 * 4]);
    }
}

extern "C" void kernel_launch(void* const* d_in, const int* in_sizes, int n_in,
                              void* d_out, int out_size, void* d_ws, size_t ws_size,
                              hipStream_t stream) {
    const float* features  = (const float*)d_in[0];
    const float* weight    = (const float*)d_in[1];
    const float* bias      = (const float*)d_in[2];
    const int* pair_in     = (const int*)d_in[3];
    // d_in[4] = pair_out — unused (pure gather)
    const int* pair_mask   = (const int*)d_in[5];
    float* out             = (float*)d_out;
    int4* rec_ws           = (int4*)d_ws;

    const int n = in_sizes[0] / 64;                       // N = 150000

    const int blocks1 = (n + 255) / 256;
    spconv_meta_kernel<<<blocks1, 256, 0, stream>>>(pair_in, pair_mask, rec_ws, n);

    const int blocks2 = (n + VPB - 1) / VPB;
    spconv_dw_kernel<<<blocks2, 256, 0, stream>>>(
        features, weight, bias, pair_in, rec_ws, out, n);
}